// Round 15
// baseline (687.580 us; speedup 1.0000x reference)
//
#include <hip/hip_runtime.h>
#include <hip/hip_fp16.h>
#include <math.h>

#define N_NODES 100000
#define N_EDGES 1600000
#define NGRAPH  256
#define YCOLS   240   // 192 conv (Yh [o][k] order) | 48 gate (A,B interleaved)
#define EPS     1e-5f
#define BNCHUNK 200   // h-rows per k_bnred block

typedef _Float16 h2v  __attribute__((ext_vector_type(2)));
typedef _Float16 f16x8 __attribute__((ext_vector_type(8)));
typedef float    f32x4 __attribute__((ext_vector_type(4)));
typedef float    f4v   __attribute__((ext_vector_type(4)));

#if defined(__has_builtin)
#if __has_builtin(__builtin_amdgcn_fdot2)
#define HAVE_FDOT2 1
#endif
#endif

__device__ inline float dot8(float4 yraw, float4 eraw, float acc) {
#ifdef HAVE_FDOT2
  union U { float4 f; h2v v[4]; } y, e;
  y.f = yraw; e.f = eraw;
  acc = __builtin_amdgcn_fdot2(y.v[0], e.v[0], acc, false);
  acc = __builtin_amdgcn_fdot2(y.v[1], e.v[1], acc, false);
  acc = __builtin_amdgcn_fdot2(y.v[2], e.v[2], acc, false);
  acc = __builtin_amdgcn_fdot2(y.v[3], e.v[3], acc, false);
#else
  const __half2* yh = reinterpret_cast<const __half2*>(&yraw);
  const __half2* eh = reinterpret_cast<const __half2*>(&eraw);
#pragma unroll
  for (int i = 0; i < 4; i++) {
    float2 a = __half22float2(yh[i]), b = __half22float2(eh[i]);
    acc += a.x * b.x + a.y * b.y;
  }
#endif
  return acc;
}

// ---------------- CSR build ----------------
__global__ void k_count(const int* __restrict__ dst, int* __restrict__ deg) {
  int e = blockIdx.x * blockDim.x + threadIdx.x;
  if (e < N_EDGES) atomicAdd(&deg[dst[e]], 1);
}

__global__ void k_scan1(const int* __restrict__ deg, int* __restrict__ part,
                        int* __restrict__ bsum) {
  __shared__ int lds[256];
  int t = threadIdx.x;
  int base = blockIdx.x * 1024 + t * 4;
  int v[4]; int s = 0;
#pragma unroll
  for (int i = 0; i < 4; i++) { int idx = base + i; v[i] = (idx < N_NODES) ? deg[idx] : 0; s += v[i]; }
  lds[t] = s; __syncthreads();
  for (int off = 1; off < 256; off <<= 1) {
    int x = (t >= off) ? lds[t - off] : 0;
    __syncthreads();
    lds[t] += x;
    __syncthreads();
  }
  int excl = lds[t] - s;
#pragma unroll
  for (int i = 0; i < 4; i++) { int idx = base + i; if (idx < N_NODES) part[idx] = excl; excl += v[i]; }
  if (t == 255) bsum[blockIdx.x] = lds[255];
}

__global__ void k_scan2(int* __restrict__ bsum, int nb) {
  __shared__ int lds[128];
  int t = threadIdx.x;
  int v = (t < nb) ? bsum[t] : 0;
  lds[t] = v; __syncthreads();
  for (int off = 1; off < 128; off <<= 1) {
    int x = (t >= off) ? lds[t - off] : 0;
    __syncthreads();
    lds[t] += x;
    __syncthreads();
  }
  if (t < nb) bsum[t] = lds[t] - v;   // exclusive
}

__global__ void k_scan3(int* __restrict__ rowptr, const int* __restrict__ bsum,
                        int* __restrict__ cursor) {
  int i = blockIdx.x * blockDim.x + threadIdx.x;
  if (i < N_NODES) {
    int v = rowptr[i] + bsum[i >> 10];
    rowptr[i] = v; cursor[i] = v;
  }
  if (i == 0) rowptr[N_NODES] = N_EDGES;
}

// fill: unroll-4 grid-stride (4 independent atomic chains/thread) + nt stores
__global__ void k_fill(const int* __restrict__ src, const int* __restrict__ dst,
                       const float* __restrict__ ea, int* __restrict__ cursor,
                       int* __restrict__ esrc, __half* __restrict__ ea_csr) {
  const int T = N_EDGES / 4;   // 400000, exact
  int tid = blockIdx.x * blockDim.x + threadIdx.x;
  if (tid >= T) return;
  int d[4], s[4];
  float4 a[4], b[4];
#pragma unroll
  for (int i = 0; i < 4; i++) {
    int e = tid + i * T;
    d[i] = dst[e];
    s[i] = src[e];
    a[i] = *reinterpret_cast<const float4*>(ea + (size_t)e * 8);
    b[i] = *reinterpret_cast<const float4*>(ea + (size_t)e * 8 + 4);
  }
  int pos[4];
#pragma unroll
  for (int i = 0; i < 4; i++) pos[i] = atomicAdd(&cursor[d[i]], 1);
#pragma unroll
  for (int i = 0; i < 4; i++) {
    __builtin_nontemporal_store(s[i], &esrc[pos[i]]);
    union { __half h[8]; f4v f; } u;
    u.h[0] = __float2half(a[i].x); u.h[1] = __float2half(a[i].y);
    u.h[2] = __float2half(a[i].z); u.h[3] = __float2half(a[i].w);
    u.h[4] = __float2half(b[i].x); u.h[5] = __float2half(b[i].y);
    u.h[6] = __float2half(b[i].z); u.h[7] = __float2half(b[i].w);
    __builtin_nontemporal_store(u.f, reinterpret_cast<f4v*>(ea_csr + (size_t)pos[i] * 8));
  }
}

// ---------------- graph segment boundaries (batch is sorted) ----------------
__global__ void k_ghist(const int* __restrict__ batch, int* __restrict__ gcnt) {
  __shared__ int lh[NGRAPH];
  int t = threadIdx.x;
  lh[t] = 0; __syncthreads();
  for (int i = blockIdx.x * 256 + t; i < N_NODES; i += gridDim.x * 256)
    atomicAdd(&lh[batch[i]], 1);
  __syncthreads();
  if (lh[t]) atomicAdd(&gcnt[t], lh[t]);
}

__global__ void k_gscan(const int* __restrict__ gcnt, int* __restrict__ gstart) {
  __shared__ int lds[NGRAPH];
  int t = threadIdx.x;
  int v = gcnt[t]; lds[t] = v; __syncthreads();
  for (int off = 1; off < NGRAPH; off <<= 1) {
    int x = (t >= off) ? lds[t - off] : 0;
    __syncthreads();
    lds[t] += x;
    __syncthreads();
  }
  gstart[t] = lds[t] - v;            // exclusive
  if (t == NGRAPH - 1) gstart[NGRAPH] = lds[NGRAPH - 1];
}

// -------- weight concat, all 3 layers in one kernel -> contiguous Wct[3] ------
__global__ void k_wcat3(const float* __restrict__ W1, const float* __restrict__ A1,
                        const float* __restrict__ B1, const float* __restrict__ W2,
                        const float* __restrict__ A2, const float* __restrict__ B2,
                        const float* __restrict__ W3, const float* __restrict__ A3,
                        const float* __restrict__ B3, __half* __restrict__ out) {
  int i = blockIdx.x * blockDim.x + threadIdx.x;
  if (i >= 3 * YCOLS * 64) return;
  int L = i / (YCOLS * 64), r = i - L * (YCOLS * 64);
  const float *W, *A, *B; int din;
  if (L == 0)      { W = W1; A = A1; B = B1; din = 64; }
  else if (L == 1) { W = W2; A = A2; B = B2; din = 48; }
  else             { W = W3; A = A3; B = B3; din = 48; }
  int p = r / 64, f = r % 64;
  float v = 0.f;
  if (f < din) {
    if (p < 192) { int o = p >> 3, k8 = p & 7; v = W[(k8 * din + f) * 24 + o]; }
    else {
      int q = p - 192, o = q >> 1;
      v = (q & 1) ? B[f * 24 + o] : A[f * 24 + o];
    }
  }
  out[i] = __float2half(v);
}

// ---------------- MFMA GEMM, operand-swapped; BN scale/shift from raw sums ----
template <int F>
__global__ __launch_bounds__(256) void k_mm(const float* __restrict__ X,
                                            const __half* __restrict__ Wct,
                                            const float* __restrict__ ssraw,
                                            const float* __restrict__ gg,
                                            const float* __restrict__ bb,
                                            const float* __restrict__ ba,
                                            const float* __restrict__ bc,
                                            __half* __restrict__ Yh,
                                            float* __restrict__ h) {
  __shared__ _Float16 sx[64][64];
  __shared__ float ssl[96];
  int t = threadIdx.x;
  int r0 = blockIdx.x * 64;
  if (ssraw != nullptr && t < 48) {
    float inv = 1.f / (float)N_NODES;
    float mean = ssraw[t] * inv;
    float var = fmaxf(ssraw[48 + t] * inv - mean * mean, 0.f);
    float sc = gg[t] * rsqrtf(var + EPS);
    ssl[t] = sc; ssl[48 + t] = bb[t] - mean * sc;
  }
  __syncthreads();
  constexpr int F4 = F / 4;
  for (int i = t; i < 64 * F4; i += 256) {
    int row = i / F4, c4 = i - row * F4;
    int grow = r0 + row;
    float4 v = make_float4(0.f, 0.f, 0.f, 0.f);
    if (grow < N_NODES) {
      v = *reinterpret_cast<const float4*>(X + (size_t)grow * F + c4 * 4);
      if (ssraw) {
        int f = c4 * 4;
        v.x = v.x * ssl[f + 0] + ssl[48 + f + 0];
        v.y = v.y * ssl[f + 1] + ssl[48 + f + 1];
        v.z = v.z * ssl[f + 2] + ssl[48 + f + 2];
        v.w = v.w * ssl[f + 3] + ssl[48 + f + 3];
      }
    }
    int c = c4 * 4;
    sx[row][c + 0] = (_Float16)v.x;
    sx[row][c + 1] = (_Float16)v.y;
    sx[row][c + 2] = (_Float16)v.z;
    sx[row][c + 3] = (_Float16)v.w;
  }
  if (F == 48) {   // zero-pad K 48..63
    for (int i = t; i < 64 * 16; i += 256) {
      int row = i / 16, k = 48 + (i % 16);
      sx[row][k] = (_Float16)0.f;
    }
  }
  __syncthreads();

  int w = t >> 6, l = t & 63;
  int lo = l & 15;
  int lk = (l >> 4) * 8;
  int g  = l >> 4;
  const f16x8 xb0 = *reinterpret_cast<const f16x8*>(&sx[w * 16 + lo][lk]);
  const f16x8 xb1 = *reinterpret_cast<const f16x8*>(&sx[w * 16 + lo][lk + 32]);
  const _Float16* wct = reinterpret_cast<const _Float16*>(Wct);
  int xg = r0 + w * 16 + lo;

#pragma unroll
  for (int tt = 0; tt < 15; tt++) {
    const f16x8 a0 = *reinterpret_cast<const f16x8*>(wct + (tt * 16 + lo) * 64 + lk);
    const f16x8 a1 = *reinterpret_cast<const f16x8*>(wct + (tt * 16 + lo) * 64 + lk + 32);
    f32x4 acc = {0.f, 0.f, 0.f, 0.f};
    acc = __builtin_amdgcn_mfma_f32_16x16x32_f16(a0, xb0, acc, 0, 0, 0);
    acc = __builtin_amdgcn_mfma_f32_16x16x32_f16(a1, xb1, acc, 0, 0, 0);
    if (xg < N_NODES) {
      if (tt < 12) {
        union { __half h4[4]; uint2 u; } pk;
        pk.h4[0] = __float2half(acc[0]);
        pk.h4[1] = __float2half(acc[1]);
        pk.h4[2] = __float2half(acc[2]);
        pk.h4[3] = __float2half(acc[3]);
        *reinterpret_cast<uint2*>(Yh + (size_t)xg * 192 + tt * 16 + g * 4) = pk.u;
      } else {
        int o0 = (tt - 12) * 8 + g * 2;
        float g0 = fmaxf(acc[0] + ba[o0], 0.f) * tanhf(acc[1] + bc[o0]);
        float g1 = fmaxf(acc[2] + ba[o0 + 1], 0.f) * tanhf(acc[3] + bc[o0 + 1]);
        *reinterpret_cast<float2*>(h + (size_t)xg * 48 + 24 + o0) = make_float2(g0, g1);
      }
    }
  }
}

// ---------------- edge aggregation (conv half of h only) ----------------
__global__ __launch_bounds__(192) void k_agg(
    const __half* __restrict__ Yh, const int* __restrict__ rowptr,
    const int* __restrict__ esrc, const __half* __restrict__ ea_csr,
    const float* __restrict__ bconv, float* __restrict__ h) {
  __shared__ float lacc[2][4][24];
  int t = threadIdx.x;
  int ln   = t / 96;            // local node 0/1
  int slot = (t / 24) % 4;      // edge slot 0..3
  int o    = t % 24;            // channel
  int n = blockIdx.x * 2 + ln;
  float acc = 0.f;
  if (n < N_NODES) {
    int r0 = rowptr[n], r1 = rowptr[n + 1];
    int idx = r0 + slot;
    for (; idx + 12 < r1; idx += 16) {
      int s0 = esrc[idx], s1 = esrc[idx + 4], s2 = esrc[idx + 8], s3 = esrc[idx + 12];
      float4 e0 = *reinterpret_cast<const float4*>(ea_csr + (size_t)idx * 8);
      float4 e1 = *reinterpret_cast<const float4*>(ea_csr + (size_t)(idx + 4) * 8);
      float4 e2 = *reinterpret_cast<const float4*>(ea_csr + (size_t)(idx + 8) * 8);
      float4 e3 = *reinterpret_cast<const float4*>(ea_csr + (size_t)(idx + 12) * 8);
      float4 y0 = *reinterpret_cast<const float4*>(Yh + (size_t)s0 * 192 + o * 8);
      float4 y1 = *reinterpret_cast<const float4*>(Yh + (size_t)s1 * 192 + o * 8);
      float4 y2 = *reinterpret_cast<const float4*>(Yh + (size_t)s2 * 192 + o * 8);
      float4 y3 = *reinterpret_cast<const float4*>(Yh + (size_t)s3 * 192 + o * 8);
      acc = dot8(y0, e0, acc);
      acc = dot8(y1, e1, acc);
      acc = dot8(y2, e2, acc);
      acc = dot8(y3, e3, acc);
    }
    for (; idx < r1; idx += 4) {
      int s0 = esrc[idx];
      float4 e0 = *reinterpret_cast<const float4*>(ea_csr + (size_t)idx * 8);
      float4 y0 = *reinterpret_cast<const float4*>(Yh + (size_t)s0 * 192 + o * 8);
      acc = dot8(y0, e0, acc);
    }
  }
  lacc[ln][slot][o] = acc;
  __syncthreads();
  if (t < 48) {
    int ln2 = t / 24, oo = t % 24;
    int n2 = blockIdx.x * 2 + ln2;
    if (n2 < N_NODES) {
      float a = lacc[ln2][0][oo] + lacc[ln2][1][oo] + lacc[ln2][2][oo] + lacc[ln2][3][oo];
      h[(size_t)n2 * 48 + oo] = fmaxf(a + bconv[oo], 0.f);
    }
  }
}

// ---------------- BN raw sums: coalesced reduce of h -> atomic into ssraw[96] -
__global__ __launch_bounds__(192) void k_bnred(const float* __restrict__ h,
                                               float* __restrict__ ssraw) {
  __shared__ float lsum[192], lsq[192];
  int t = threadIdx.x;
  int rp = t / 48, c = t % 48;
  int r0 = blockIdx.x * BNCHUNK;
  int r1 = r0 + BNCHUNK; if (r1 > N_NODES) r1 = N_NODES;
  float s = 0.f, q = 0.f;
  for (int r = r0 + rp; r < r1; r += 4) {
    float v = h[(size_t)r * 48 + c];
    s += v; q += v * v;
  }
  lsum[t] = s; lsq[t] = q; __syncthreads();
  if (t < 48) {
    float S = lsum[t] + lsum[t + 48] + lsum[t + 96] + lsum[t + 144];
    float Q = lsq[t] + lsq[t + 48] + lsq[t + 96] + lsq[t + 144];
    atomicAdd(&ssraw[t], S);
    atomicAdd(&ssraw[48 + t], Q);
  }
}

// ------- fused mean-pool (BN3 fold from raw sums) + MLP head ----------------
__global__ __launch_bounds__(240) void k_poolmlp(
    const float* __restrict__ h, const int* __restrict__ gstart,
    const float* __restrict__ ssraw, const float* __restrict__ gg,
    const float* __restrict__ bb, const float* __restrict__ F1,
    const float* __restrict__ f1, const float* __restrict__ F2,
    const float* __restrict__ f2, float* __restrict__ out) {
  __shared__ float acc[240];
  __shared__ float ssl[96];
  __shared__ float p[48];
  int g = blockIdx.x, t = threadIdx.x;
  if (t < 48) {
    float inv = 1.f / (float)N_NODES;
    float mean = ssraw[t] * inv;
    float var = fmaxf(ssraw[48 + t] * inv - mean * mean, 0.f);
    float sc = gg[t] * rsqrtf(var + EPS);
    ssl[t] = sc; ssl[48 + t] = bb[t] - mean * sc;
  }
  int o = t % 48, r = t / 48;
  int n0 = gstart[g], n1 = gstart[g + 1];
  float s = 0.f;
  for (int n = n0 + r; n < n1; n += 5) s += h[(size_t)n * 48 + o];
  acc[t] = s; __syncthreads();
  if (t < 48) {
    float tot = acc[t] + acc[t + 48] + acc[t + 96] + acc[t + 144] + acc[t + 192];
    float mean = tot / fmaxf((float)(n1 - n0), 1.f);
    p[t] = mean * ssl[t] + ssl[48 + t];
  }
  __syncthreads();
  if (t < 64) {
    float rr = 0.f;
    if (t < 32) {
      float sum = f1[t];
#pragma unroll
      for (int c = 0; c < 48; c++) sum += p[c] * F1[c * 32 + t];
      rr = fmaxf(sum, 0.f) * F2[t];
    }
    for (int off = 32; off > 0; off >>= 1) rr += __shfl_down(rr, off, 64);
    if (t == 0) out[g] = rr + f2[0];
  }
}

extern "C" void kernel_launch(void* const* d_in, const int* in_sizes, int n_in,
                              void* d_out, int out_size, void* d_ws, size_t ws_size,
                              hipStream_t stream) {
  const float* x          = (const float*)d_in[0];
  const int*   edge_index = (const int*)d_in[1];
  const float* ea         = (const float*)d_in[2];
  const int*   batch      = (const int*)d_in[3];
  const float *W[3], *bcv[3], *A[3], *ba[3], *B[3], *bc[3], *g[3], *be[3];
  for (int l = 0; l < 3; l++) {
    int base = 4 + l * 8;
    W[l]   = (const float*)d_in[base + 0];
    bcv[l] = (const float*)d_in[base + 1];
    A[l]   = (const float*)d_in[base + 2];
    ba[l]  = (const float*)d_in[base + 3];
    B[l]   = (const float*)d_in[base + 4];
    bc[l]  = (const float*)d_in[base + 5];
    g[l]   = (const float*)d_in[base + 6];
    be[l]  = (const float*)d_in[base + 7];
  }
  const float* F1 = (const float*)d_in[28];
  const float* f1 = (const float*)d_in[29];
  const float* F2 = (const float*)d_in[30];
  const float* f2 = (const float*)d_in[31];
  const int* src = edge_index;
  const int* dst = edge_index + N_EDGES;

  char* w = (char*)d_ws;
  auto alloc = [&](size_t bytes) -> char* {
    char* p = w;
    w += (bytes + 255) & ~(size_t)255;
    return p;
  };
  int nagg = (N_NODES + 1) / 2;                   // 50000 blocks, 2 nodes each
  int nred = (N_NODES + BNCHUNK - 1) / BNCHUNK;   // 500 stage-1 blocks

  int*    rowptr  = (int*)alloc((N_NODES + 1) * 4);
  int*    cursor  = (int*)alloc((size_t)N_NODES * 4);
  int*    deg     = (int*)alloc((size_t)N_NODES * 4);
  int*    bsum    = (int*)alloc(128 * 4);
  int*    esrc    = (int*)alloc((size_t)N_EDGES * 4);
  __half* ea_csr  = (__half*)alloc((size_t)N_EDGES * 8 * 2);
  int*    gcnt    = (int*)alloc(NGRAPH * 4);
  int*    gstart  = (int*)alloc((NGRAPH + 1) * 4);
  __half* Wct     = (__half*)alloc((size_t)3 * YCOLS * 64 * 2);
  __half* Wct1    = Wct;
  __half* Wct2    = Wct + YCOLS * 64;
  __half* Wct3    = Wct + 2 * YCOLS * 64;
  __half* Yh      = (__half*)alloc((size_t)N_NODES * 192 * 2);
  float*  h0      = (float*)alloc((size_t)N_NODES * 48 * 4);
  float*  h1      = (float*)alloc((size_t)N_NODES * 48 * 4);
  float*  ssraw   = (float*)alloc(3 * 96 * 4);
  float*  ssraw1  = ssraw;
  float*  ssraw2  = ssraw + 96;
  float*  ssraw3  = ssraw + 192;

  hipMemsetAsync(deg, 0, (size_t)N_NODES * 4, stream);
  hipMemsetAsync(gcnt, 0, NGRAPH * 4, stream);
  hipMemsetAsync(ssraw, 0, 3 * 96 * 4, stream);

  k_count<<<(N_EDGES + 255) / 256, 256, 0, stream>>>(dst, deg);
  int nchunk = (N_NODES + 1023) / 1024;
  k_scan1<<<nchunk, 256, 0, stream>>>(deg, rowptr, bsum);
  k_scan2<<<1, 128, 0, stream>>>(bsum, nchunk);
  k_scan3<<<(N_NODES + 255) / 256, 256, 0, stream>>>(rowptr, bsum, cursor);
  k_fill<<<(N_EDGES / 4 + 255) / 256, 256, 0, stream>>>(src, dst, ea, cursor, esrc, ea_csr);

  k_ghist<<<64, 256, 0, stream>>>(batch, gcnt);
  k_gscan<<<1, NGRAPH, 0, stream>>>(gcnt, gstart);

  k_wcat3<<<(3 * YCOLS * 64 + 255) / 256, 256, 0, stream>>>(
      W[0], A[0], B[0], W[1], A[1], B[1], W[2], A[2], B[2], Wct);

  int nmm = (N_NODES + 63) / 64;   // 1563 blocks, 64 rows each

  // layer 1: x -> h0
  k_mm<64><<<nmm, 256, 0, stream>>>(x, Wct1, nullptr, nullptr, nullptr, ba[0], bc[0], Yh, h0);
  k_agg<<<nagg, 192, 0, stream>>>(Yh, rowptr, esrc, ea_csr, bcv[0], h0);
  k_bnred<<<nred, 192, 0, stream>>>(h0, ssraw1);
  // layer 2: h0 (BN1 fold) -> h1
  k_mm<48><<<nmm, 256, 0, stream>>>(h0, Wct2, ssraw1, g[0], be[0], ba[1], bc[1], Yh, h1);
  k_agg<<<nagg, 192, 0, stream>>>(Yh, rowptr, esrc, ea_csr, bcv[1], h1);
  k_bnred<<<nred, 192, 0, stream>>>(h1, ssraw2);
  // layer 3: h1 (BN2 fold) -> h0
  k_mm<48><<<nmm, 256, 0, stream>>>(h1, Wct3, ssraw2, g[1], be[1], ba[2], bc[2], Yh, h0);
  k_agg<<<nagg, 192, 0, stream>>>(Yh, rowptr, esrc, ea_csr, bcv[2], h0);
  k_bnred<<<nred, 192, 0, stream>>>(h0, ssraw3);

  // fused pool (BN3 fold) + MLP head
  k_poolmlp<<<NGRAPH, 240, 0, stream>>>(h0, gstart, ssraw3, g[2], be[2],
                                        F1, f1, F2, f2, (float*)d_out);
}

// Round 16
// 653.547 us; speedup vs baseline: 1.0521x; 1.0521x over previous
//
#include <hip/hip_runtime.h>
#include <hip/hip_fp16.h>
#include <math.h>

#define N_NODES 100000
#define N_EDGES 1600000
#define NGRAPH  256
#define YCOLS   240   // 192 conv (Yh [o][k] order) | 48 gate (A,B interleaved)
#define EPS     1e-5f
#define BNCHUNK 200   // h-rows per k_bnred block

typedef _Float16 h2v  __attribute__((ext_vector_type(2)));
typedef _Float16 f16x8 __attribute__((ext_vector_type(8)));
typedef float    f32x4 __attribute__((ext_vector_type(4)));

#if defined(__has_builtin)
#if __has_builtin(__builtin_amdgcn_fdot2)
#define HAVE_FDOT2 1
#endif
#endif

__device__ inline float dot8(float4 yraw, float4 eraw, float acc) {
#ifdef HAVE_FDOT2
  union U { float4 f; h2v v[4]; } y, e;
  y.f = yraw; e.f = eraw;
  acc = __builtin_amdgcn_fdot2(y.v[0], e.v[0], acc, false);
  acc = __builtin_amdgcn_fdot2(y.v[1], e.v[1], acc, false);
  acc = __builtin_amdgcn_fdot2(y.v[2], e.v[2], acc, false);
  acc = __builtin_amdgcn_fdot2(y.v[3], e.v[3], acc, false);
#else
  const __half2* yh = reinterpret_cast<const __half2*>(&yraw);
  const __half2* eh = reinterpret_cast<const __half2*>(&eraw);
#pragma unroll
  for (int i = 0; i < 4; i++) {
    float2 a = __half22float2(yh[i]), b = __half22float2(eh[i]);
    acc += a.x * b.x + a.y * b.y;
  }
#endif
  return acc;
}

// ---------------- CSR build ----------------
__global__ void k_count(const int* __restrict__ dst, int* __restrict__ deg) {
  int e = blockIdx.x * blockDim.x + threadIdx.x;
  if (e < N_EDGES) atomicAdd(&deg[dst[e]], 1);
}

__global__ void k_scan1(const int* __restrict__ deg, int* __restrict__ part,
                        int* __restrict__ bsum) {
  __shared__ int lds[256];
  int t = threadIdx.x;
  int base = blockIdx.x * 1024 + t * 4;
  int v[4]; int s = 0;
#pragma unroll
  for (int i = 0; i < 4; i++) { int idx = base + i; v[i] = (idx < N_NODES) ? deg[idx] : 0; s += v[i]; }
  lds[t] = s; __syncthreads();
  for (int off = 1; off < 256; off <<= 1) {
    int x = (t >= off) ? lds[t - off] : 0;
    __syncthreads();
    lds[t] += x;
    __syncthreads();
  }
  int excl = lds[t] - s;
#pragma unroll
  for (int i = 0; i < 4; i++) { int idx = base + i; if (idx < N_NODES) part[idx] = excl; excl += v[i]; }
  if (t == 255) bsum[blockIdx.x] = lds[255];
}

__global__ void k_scan2(int* __restrict__ bsum, int nb) {
  __shared__ int lds[128];
  int t = threadIdx.x;
  int v = (t < nb) ? bsum[t] : 0;
  lds[t] = v; __syncthreads();
  for (int off = 1; off < 128; off <<= 1) {
    int x = (t >= off) ? lds[t - off] : 0;
    __syncthreads();
    lds[t] += x;
    __syncthreads();
  }
  if (t < nb) bsum[t] = lds[t] - v;   // exclusive
}

__global__ void k_scan3(int* __restrict__ rowptr, const int* __restrict__ bsum,
                        int* __restrict__ cursor) {
  int i = blockIdx.x * blockDim.x + threadIdx.x;
  if (i < N_NODES) {
    int v = rowptr[i] + bsum[i >> 10];
    rowptr[i] = v; cursor[i] = v;
  }
  if (i == 0) rowptr[N_NODES] = N_EDGES;
}

// combined fill (round-7/12 empirical best): 1 edge/thread, plain stores
__global__ void k_fill(const int* __restrict__ src, const int* __restrict__ dst,
                       const float* __restrict__ ea, int* __restrict__ cursor,
                       int* __restrict__ esrc, __half* __restrict__ ea_csr) {
  int e = blockIdx.x * blockDim.x + threadIdx.x;
  if (e < N_EDGES) {
    int d = dst[e];
    int pos = atomicAdd(&cursor[d], 1);
    esrc[pos] = src[e];
    float4 a = *reinterpret_cast<const float4*>(ea + (size_t)e * 8);
    float4 b = *reinterpret_cast<const float4*>(ea + (size_t)e * 8 + 4);
    union { __half h[8]; float4 f; } u;
    u.h[0] = __float2half(a.x); u.h[1] = __float2half(a.y);
    u.h[2] = __float2half(a.z); u.h[3] = __float2half(a.w);
    u.h[4] = __float2half(b.x); u.h[5] = __float2half(b.y);
    u.h[6] = __float2half(b.z); u.h[7] = __float2half(b.w);
    *reinterpret_cast<float4*>(ea_csr + (size_t)pos * 8) = u.f;
  }
}

// ---------------- graph segment boundaries (batch is sorted) ----------------
__global__ void k_ghist(const int* __restrict__ batch, int* __restrict__ gcnt) {
  __shared__ int lh[NGRAPH];
  int t = threadIdx.x;
  lh[t] = 0; __syncthreads();
  for (int i = blockIdx.x * 256 + t; i < N_NODES; i += gridDim.x * 256)
    atomicAdd(&lh[batch[i]], 1);
  __syncthreads();
  if (lh[t]) atomicAdd(&gcnt[t], lh[t]);
}

__global__ void k_gscan(const int* __restrict__ gcnt, int* __restrict__ gstart) {
  __shared__ int lds[NGRAPH];
  int t = threadIdx.x;
  int v = gcnt[t]; lds[t] = v; __syncthreads();
  for (int off = 1; off < NGRAPH; off <<= 1) {
    int x = (t >= off) ? lds[t - off] : 0;
    __syncthreads();
    lds[t] += x;
    __syncthreads();
  }
  gstart[t] = lds[t] - v;            // exclusive
  if (t == NGRAPH - 1) gstart[NGRAPH] = lds[NGRAPH - 1];
}

// -------- weight concat, all 3 layers in one kernel -> contiguous Wct[3] ------
__global__ void k_wcat3(const float* __restrict__ W1, const float* __restrict__ A1,
                        const float* __restrict__ B1, const float* __restrict__ W2,
                        const float* __restrict__ A2, const float* __restrict__ B2,
                        const float* __restrict__ W3, const float* __restrict__ A3,
                        const float* __restrict__ B3, __half* __restrict__ out) {
  int i = blockIdx.x * blockDim.x + threadIdx.x;
  if (i >= 3 * YCOLS * 64) return;
  int L = i / (YCOLS * 64), r = i - L * (YCOLS * 64);
  const float *W, *A, *B; int din;
  if (L == 0)      { W = W1; A = A1; B = B1; din = 64; }
  else if (L == 1) { W = W2; A = A2; B = B2; din = 48; }
  else             { W = W3; A = A3; B = B3; din = 48; }
  int p = r / 64, f = r % 64;
  float v = 0.f;
  if (f < din) {
    if (p < 192) { int o = p >> 3, k8 = p & 7; v = W[(k8 * din + f) * 24 + o]; }
    else {
      int q = p - 192, o = q >> 1;
      v = (q & 1) ? B[f * 24 + o] : A[f * 24 + o];
    }
  }
  out[i] = __float2half(v);
}

// ---------------- MFMA GEMM, operand-swapped; BN scale/shift from raw sums ----
template <int F>
__global__ __launch_bounds__(256) void k_mm(const float* __restrict__ X,
                                            const __half* __restrict__ Wct,
                                            const float* __restrict__ ssraw,
                                            const float* __restrict__ gg,
                                            const float* __restrict__ bb,
                                            const float* __restrict__ ba,
                                            const float* __restrict__ bc,
                                            __half* __restrict__ Yh,
                                            float* __restrict__ h) {
  __shared__ _Float16 sx[64][64];
  __shared__ float ssl[96];
  int t = threadIdx.x;
  int r0 = blockIdx.x * 64;
  if (ssraw != nullptr && t < 48) {
    float inv = 1.f / (float)N_NODES;
    float mean = ssraw[t] * inv;
    float var = fmaxf(ssraw[48 + t] * inv - mean * mean, 0.f);
    float sc = gg[t] * rsqrtf(var + EPS);
    ssl[t] = sc; ssl[48 + t] = bb[t] - mean * sc;
  }
  __syncthreads();
  constexpr int F4 = F / 4;
  for (int i = t; i < 64 * F4; i += 256) {
    int row = i / F4, c4 = i - row * F4;
    int grow = r0 + row;
    float4 v = make_float4(0.f, 0.f, 0.f, 0.f);
    if (grow < N_NODES) {
      v = *reinterpret_cast<const float4*>(X + (size_t)grow * F + c4 * 4);
      if (ssraw) {
        int f = c4 * 4;
        v.x = v.x * ssl[f + 0] + ssl[48 + f + 0];
        v.y = v.y * ssl[f + 1] + ssl[48 + f + 1];
        v.z = v.z * ssl[f + 2] + ssl[48 + f + 2];
        v.w = v.w * ssl[f + 3] + ssl[48 + f + 3];
      }
    }
    int c = c4 * 4;
    sx[row][c + 0] = (_Float16)v.x;
    sx[row][c + 1] = (_Float16)v.y;
    sx[row][c + 2] = (_Float16)v.z;
    sx[row][c + 3] = (_Float16)v.w;
  }
  if (F == 48) {   // zero-pad K 48..63
    for (int i = t; i < 64 * 16; i += 256) {
      int row = i / 16, k = 48 + (i % 16);
      sx[row][k] = (_Float16)0.f;
    }
  }
  __syncthreads();

  int w = t >> 6, l = t & 63;
  int lo = l & 15;
  int lk = (l >> 4) * 8;
  int g  = l >> 4;
  const f16x8 xb0 = *reinterpret_cast<const f16x8*>(&sx[w * 16 + lo][lk]);
  const f16x8 xb1 = *reinterpret_cast<const f16x8*>(&sx[w * 16 + lo][lk + 32]);
  const _Float16* wct = reinterpret_cast<const _Float16*>(Wct);
  int xg = r0 + w * 16 + lo;

#pragma unroll
  for (int tt = 0; tt < 15; tt++) {
    const f16x8 a0 = *reinterpret_cast<const f16x8*>(wct + (tt * 16 + lo) * 64 + lk);
    const f16x8 a1 = *reinterpret_cast<const f16x8*>(wct + (tt * 16 + lo) * 64 + lk + 32);
    f32x4 acc = {0.f, 0.f, 0.f, 0.f};
    acc = __builtin_amdgcn_mfma_f32_16x16x32_f16(a0, xb0, acc, 0, 0, 0);
    acc = __builtin_amdgcn_mfma_f32_16x16x32_f16(a1, xb1, acc, 0, 0, 0);
    if (xg < N_NODES) {
      if (tt < 12) {
        union { __half h4[4]; uint2 u; } pk;
        pk.h4[0] = __float2half(acc[0]);
        pk.h4[1] = __float2half(acc[1]);
        pk.h4[2] = __float2half(acc[2]);
        pk.h4[3] = __float2half(acc[3]);
        *reinterpret_cast<uint2*>(Yh + (size_t)xg * 192 + tt * 16 + g * 4) = pk.u;
      } else {
        int o0 = (tt - 12) * 8 + g * 2;
        float g0 = fmaxf(acc[0] + ba[o0], 0.f) * tanhf(acc[1] + bc[o0]);
        float g1 = fmaxf(acc[2] + ba[o0 + 1], 0.f) * tanhf(acc[3] + bc[o0 + 1]);
        *reinterpret_cast<float2*>(h + (size_t)xg * 48 + 24 + o0) = make_float2(g0, g1);
      }
    }
  }
}

// ---------------- edge aggregation (conv half of h only) ----------------
__global__ __launch_bounds__(192) void k_agg(
    const __half* __restrict__ Yh, const int* __restrict__ rowptr,
    const int* __restrict__ esrc, const __half* __restrict__ ea_csr,
    const float* __restrict__ bconv, float* __restrict__ h) {
  __shared__ float lacc[2][4][24];
  int t = threadIdx.x;
  int ln   = t / 96;            // local node 0/1
  int slot = (t / 24) % 4;      // edge slot 0..3
  int o    = t % 24;            // channel
  int n = blockIdx.x * 2 + ln;
  float acc = 0.f;
  if (n < N_NODES) {
    int r0 = rowptr[n], r1 = rowptr[n + 1];
    int idx = r0 + slot;
    for (; idx + 12 < r1; idx += 16) {
      int s0 = esrc[idx], s1 = esrc[idx + 4], s2 = esrc[idx + 8], s3 = esrc[idx + 12];
      float4 e0 = *reinterpret_cast<const float4*>(ea_csr + (size_t)idx * 8);
      float4 e1 = *reinterpret_cast<const float4*>(ea_csr + (size_t)(idx + 4) * 8);
      float4 e2 = *reinterpret_cast<const float4*>(ea_csr + (size_t)(idx + 8) * 8);
      float4 e3 = *reinterpret_cast<const float4*>(ea_csr + (size_t)(idx + 12) * 8);
      float4 y0 = *reinterpret_cast<const float4*>(Yh + (size_t)s0 * 192 + o * 8);
      float4 y1 = *reinterpret_cast<const float4*>(Yh + (size_t)s1 * 192 + o * 8);
      float4 y2 = *reinterpret_cast<const float4*>(Yh + (size_t)s2 * 192 + o * 8);
      float4 y3 = *reinterpret_cast<const float4*>(Yh + (size_t)s3 * 192 + o * 8);
      acc = dot8(y0, e0, acc);
      acc = dot8(y1, e1, acc);
      acc = dot8(y2, e2, acc);
      acc = dot8(y3, e3, acc);
    }
    for (; idx < r1; idx += 4) {
      int s0 = esrc[idx];
      float4 e0 = *reinterpret_cast<const float4*>(ea_csr + (size_t)idx * 8);
      float4 y0 = *reinterpret_cast<const float4*>(Yh + (size_t)s0 * 192 + o * 8);
      acc = dot8(y0, e0, acc);
    }
  }
  lacc[ln][slot][o] = acc;
  __syncthreads();
  if (t < 48) {
    int ln2 = t / 24, oo = t % 24;
    int n2 = blockIdx.x * 2 + ln2;
    if (n2 < N_NODES) {
      float a = lacc[ln2][0][oo] + lacc[ln2][1][oo] + lacc[ln2][2][oo] + lacc[ln2][3][oo];
      h[(size_t)n2 * 48 + oo] = fmaxf(a + bconv[oo], 0.f);
    }
  }
}

// ---------------- BN raw sums: coalesced reduce of h -> atomic into ssraw[96] -
__global__ __launch_bounds__(192) void k_bnred(const float* __restrict__ h,
                                               float* __restrict__ ssraw) {
  __shared__ float lsum[192], lsq[192];
  int t = threadIdx.x;
  int rp = t / 48, c = t % 48;
  int r0 = blockIdx.x * BNCHUNK;
  int r1 = r0 + BNCHUNK; if (r1 > N_NODES) r1 = N_NODES;
  float s = 0.f, q = 0.f;
  for (int r = r0 + rp; r < r1; r += 4) {
    float v = h[(size_t)r * 48 + c];
    s += v; q += v * v;
  }
  lsum[t] = s; lsq[t] = q; __syncthreads();
  if (t < 48) {
    float S = lsum[t] + lsum[t + 48] + lsum[t + 96] + lsum[t + 144];
    float Q = lsq[t] + lsq[t + 48] + lsq[t + 96] + lsq[t + 144];
    atomicAdd(&ssraw[t], S);
    atomicAdd(&ssraw[48 + t], Q);
  }
}

// ------- fused mean-pool (BN3 fold from raw sums) + MLP head ----------------
__global__ __launch_bounds__(240) void k_poolmlp(
    const float* __restrict__ h, const int* __restrict__ gstart,
    const float* __restrict__ ssraw, const float* __restrict__ gg,
    const float* __restrict__ bb, const float* __restrict__ F1,
    const float* __restrict__ f1, const float* __restrict__ F2,
    const float* __restrict__ f2, float* __restrict__ out) {
  __shared__ float acc[240];
  __shared__ float ssl[96];
  __shared__ float p[48];
  int g = blockIdx.x, t = threadIdx.x;
  if (t < 48) {
    float inv = 1.f / (float)N_NODES;
    float mean = ssraw[t] * inv;
    float var = fmaxf(ssraw[48 + t] * inv - mean * mean, 0.f);
    float sc = gg[t] * rsqrtf(var + EPS);
    ssl[t] = sc; ssl[48 + t] = bb[t] - mean * sc;
  }
  int o = t % 48, r = t / 48;
  int n0 = gstart[g], n1 = gstart[g + 1];
  float s = 0.f;
  for (int n = n0 + r; n < n1; n += 5) s += h[(size_t)n * 48 + o];
  acc[t] = s; __syncthreads();
  if (t < 48) {
    float tot = acc[t] + acc[t + 48] + acc[t + 96] + acc[t + 144] + acc[t + 192];
    float mean = tot / fmaxf((float)(n1 - n0), 1.f);
    p[t] = mean * ssl[t] + ssl[48 + t];
  }
  __syncthreads();
  if (t < 64) {
    float rr = 0.f;
    if (t < 32) {
      float sum = f1[t];
#pragma unroll
      for (int c = 0; c < 48; c++) sum += p[c] * F1[c * 32 + t];
      rr = fmaxf(sum, 0.f) * F2[t];
    }
    for (int off = 32; off > 0; off >>= 1) rr += __shfl_down(rr, off, 64);
    if (t == 0) out[g] = rr + f2[0];
  }
}

extern "C" void kernel_launch(void* const* d_in, const int* in_sizes, int n_in,
                              void* d_out, int out_size, void* d_ws, size_t ws_size,
                              hipStream_t stream) {
  const float* x          = (const float*)d_in[0];
  const int*   edge_index = (const int*)d_in[1];
  const float* ea         = (const float*)d_in[2];
  const int*   batch      = (const int*)d_in[3];
  const float *W[3], *bcv[3], *A[3], *ba[3], *B[3], *bc[3], *g[3], *be[3];
  for (int l = 0; l < 3; l++) {
    int base = 4 + l * 8;
    W[l]   = (const float*)d_in[base + 0];
    bcv[l] = (const float*)d_in[base + 1];
    A[l]   = (const float*)d_in[base + 2];
    ba[l]  = (const float*)d_in[base + 3];
    B[l]   = (const float*)d_in[base + 4];
    bc[l]  = (const float*)d_in[base + 5];
    g[l]   = (const float*)d_in[base + 6];
    be[l]  = (const float*)d_in[base + 7];
  }
  const float* F1 = (const float*)d_in[28];
  const float* f1 = (const float*)d_in[29];
  const float* F2 = (const float*)d_in[30];
  const float* f2 = (const float*)d_in[31];
  const int* src = edge_index;
  const int* dst = edge_index + N_EDGES;

  char* w = (char*)d_ws;
  auto alloc = [&](size_t bytes) -> char* {
    char* p = w;
    w += (bytes + 255) & ~(size_t)255;
    return p;
  };
  int nagg = (N_NODES + 1) / 2;                   // 50000 blocks, 2 nodes each
  int nred = (N_NODES + BNCHUNK - 1) / BNCHUNK;   // 500 stage-1 blocks

  int*    rowptr  = (int*)alloc((N_NODES + 1) * 4);
  int*    cursor  = (int*)alloc((size_t)N_NODES * 4);
  int*    deg     = (int*)alloc((size_t)N_NODES * 4);
  int*    bsum    = (int*)alloc(128 * 4);
  int*    esrc    = (int*)alloc((size_t)N_EDGES * 4);
  __half* ea_csr  = (__half*)alloc((size_t)N_EDGES * 8 * 2);
  int*    gcnt    = (int*)alloc(NGRAPH * 4);
  int*    gstart  = (int*)alloc((NGRAPH + 1) * 4);
  __half* Wct     = (__half*)alloc((size_t)3 * YCOLS * 64 * 2);
  __half* Wct1    = Wct;
  __half* Wct2    = Wct + YCOLS * 64;
  __half* Wct3    = Wct + 2 * YCOLS * 64;
  __half* Yh      = (__half*)alloc((size_t)N_NODES * 192 * 2);
  float*  h0      = (float*)alloc((size_t)N_NODES * 48 * 4);
  float*  h1      = (float*)alloc((size_t)N_NODES * 48 * 4);
  float*  ssraw   = (float*)alloc(3 * 96 * 4);
  float*  ssraw1  = ssraw;
  float*  ssraw2  = ssraw + 96;
  float*  ssraw3  = ssraw + 192;

  hipMemsetAsync(deg, 0, (size_t)N_NODES * 4, stream);
  hipMemsetAsync(gcnt, 0, NGRAPH * 4, stream);
  hipMemsetAsync(ssraw, 0, 3 * 96 * 4, stream);

  k_count<<<(N_EDGES + 255) / 256, 256, 0, stream>>>(dst, deg);
  int nchunk = (N_NODES + 1023) / 1024;
  k_scan1<<<nchunk, 256, 0, stream>>>(deg, rowptr, bsum);
  k_scan2<<<1, 128, 0, stream>>>(bsum, nchunk);
  k_scan3<<<(N_NODES + 255) / 256, 256, 0, stream>>>(rowptr, bsum, cursor);
  k_fill<<<(N_EDGES + 255) / 256, 256, 0, stream>>>(src, dst, ea, cursor, esrc, ea_csr);

  k_ghist<<<64, 256, 0, stream>>>(batch, gcnt);
  k_gscan<<<1, NGRAPH, 0, stream>>>(gcnt, gstart);

  k_wcat3<<<(3 * YCOLS * 64 + 255) / 256, 256, 0, stream>>>(
      W[0], A[0], B[0], W[1], A[1], B[1], W[2], A[2], B[2], Wct);

  int nmm = (N_NODES + 63) / 64;   // 1563 blocks, 64 rows each

  // layer 1: x -> h0
  k_mm<64><<<nmm, 256, 0, stream>>>(x, Wct1, nullptr, nullptr, nullptr, ba[0], bc[0], Yh, h0);
  k_agg<<<nagg, 192, 0, stream>>>(Yh, rowptr, esrc, ea_csr, bcv[0], h0);
  k_bnred<<<nred, 192, 0, stream>>>(h0, ssraw1);
  // layer 2: h0 (BN1 fold) -> h1
  k_mm<48><<<nmm, 256, 0, stream>>>(h0, Wct2, ssraw1, g[0], be[0], ba[1], bc[1], Yh, h1);
  k_agg<<<nagg, 192, 0, stream>>>(Yh, rowptr, esrc, ea_csr, bcv[1], h1);
  k_bnred<<<nred, 192, 0, stream>>>(h1, ssraw2);
  // layer 3: h1 (BN2 fold) -> h0
  k_mm<48><<<nmm, 256, 0, stream>>>(h1, Wct3, ssraw2, g[1], be[1], ba[2], bc[2], Yh, h0);
  k_agg<<<nagg, 192, 0, stream>>>(Yh, rowptr, esrc, ea_csr, bcv[2], h0);
  k_bnred<<<nred, 192, 0, stream>>>(h0, ssraw3);

  // fused pool (BN3 fold) + MLP head
  k_poolmlp<<<NGRAPH, 240, 0, stream>>>(h0, gstart, ssraw3, g[2], be[2],
                                        F1, f1, F2, f2, (float*)d_out);
}

// Round 17
// 633.991 us; speedup vs baseline: 1.0845x; 1.0308x over previous
//
#include <hip/hip_runtime.h>
#include <hip/hip_fp16.h>
#include <math.h>

#define N_NODES 100000
#define N_EDGES 1600000
#define NGRAPH  256
#define YCOLS   240   // 192 conv (Yh [o][k] order) | 48 gate (A,B interleaved)
#define EPS     1e-5f
#define BNCHUNK 200   // h-rows per k_bnred1 block

typedef _Float16 h2v  __attribute__((ext_vector_type(2)));
typedef _Float16 f16x8 __attribute__((ext_vector_type(8)));
typedef float    f32x4 __attribute__((ext_vector_type(4)));

#if defined(__has_builtin)
#if __has_builtin(__builtin_amdgcn_fdot2)
#define HAVE_FDOT2 1
#endif
#endif

__device__ inline float dot8(float4 yraw, float4 eraw, float acc) {
#ifdef HAVE_FDOT2
  union U { float4 f; h2v v[4]; } y, e;
  y.f = yraw; e.f = eraw;
  acc = __builtin_amdgcn_fdot2(y.v[0], e.v[0], acc, false);
  acc = __builtin_amdgcn_fdot2(y.v[1], e.v[1], acc, false);
  acc = __builtin_amdgcn_fdot2(y.v[2], e.v[2], acc, false);
  acc = __builtin_amdgcn_fdot2(y.v[3], e.v[3], acc, false);
#else
  const __half2* yh = reinterpret_cast<const __half2*>(&yraw);
  const __half2* eh = reinterpret_cast<const __half2*>(&eraw);
#pragma unroll
  for (int i = 0; i < 4; i++) {
    float2 a = __half22float2(yh[i]), b = __half22float2(eh[i]);
    acc += a.x * b.x + a.y * b.y;
  }
#endif
  return acc;
}

// ---------------- CSR build ----------------
__global__ void k_count(const int* __restrict__ dst, int* __restrict__ deg) {
  int e = blockIdx.x * blockDim.x + threadIdx.x;
  if (e < N_EDGES) atomicAdd(&deg[dst[e]], 1);
}

__global__ void k_scan1(const int* __restrict__ deg, int* __restrict__ part,
                        int* __restrict__ bsum) {
  __shared__ int lds[256];
  int t = threadIdx.x;
  int base = blockIdx.x * 1024 + t * 4;
  int v[4]; int s = 0;
#pragma unroll
  for (int i = 0; i < 4; i++) { int idx = base + i; v[i] = (idx < N_NODES) ? deg[idx] : 0; s += v[i]; }
  lds[t] = s; __syncthreads();
  for (int off = 1; off < 256; off <<= 1) {
    int x = (t >= off) ? lds[t - off] : 0;
    __syncthreads();
    lds[t] += x;
    __syncthreads();
  }
  int excl = lds[t] - s;
#pragma unroll
  for (int i = 0; i < 4; i++) { int idx = base + i; if (idx < N_NODES) part[idx] = excl; excl += v[i]; }
  if (t == 255) bsum[blockIdx.x] = lds[255];
}

__global__ void k_scan2(int* __restrict__ bsum, int nb) {
  __shared__ int lds[128];
  int t = threadIdx.x;
  int v = (t < nb) ? bsum[t] : 0;
  lds[t] = v; __syncthreads();
  for (int off = 1; off < 128; off <<= 1) {
    int x = (t >= off) ? lds[t - off] : 0;
    __syncthreads();
    lds[t] += x;
    __syncthreads();
  }
  if (t < nb) bsum[t] = lds[t] - v;   // exclusive
}

__global__ void k_scan3(int* __restrict__ rowptr, const int* __restrict__ bsum,
                        int* __restrict__ cursor) {
  int i = blockIdx.x * blockDim.x + threadIdx.x;
  if (i < N_NODES) {
    int v = rowptr[i] + bsum[i >> 10];
    rowptr[i] = v; cursor[i] = v;
  }
  if (i == 0) rowptr[N_NODES] = N_EDGES;
}

// combined fill (empirical best): esrc + ea fp16 permuted into CSR order
__global__ void k_fill(const int* __restrict__ src, const int* __restrict__ dst,
                       const float* __restrict__ ea, int* __restrict__ cursor,
                       int* __restrict__ esrc, __half* __restrict__ ea_csr) {
  int e = blockIdx.x * blockDim.x + threadIdx.x;
  if (e < N_EDGES) {
    int d = dst[e];
    int pos = atomicAdd(&cursor[d], 1);
    esrc[pos] = src[e];
    float4 a = *reinterpret_cast<const float4*>(ea + (size_t)e * 8);
    float4 b = *reinterpret_cast<const float4*>(ea + (size_t)e * 8 + 4);
    union { __half h[8]; float4 f; } u;
    u.h[0] = __float2half(a.x); u.h[1] = __float2half(a.y);
    u.h[2] = __float2half(a.z); u.h[3] = __float2half(a.w);
    u.h[4] = __float2half(b.x); u.h[5] = __float2half(b.y);
    u.h[6] = __float2half(b.z); u.h[7] = __float2half(b.w);
    *reinterpret_cast<float4*>(ea_csr + (size_t)pos * 8) = u.f;
  }
}

// ---------------- graph segment boundaries (batch is sorted) ----------------
__global__ void k_ghist(const int* __restrict__ batch, int* __restrict__ gcnt) {
  __shared__ int lh[NGRAPH];
  int t = threadIdx.x;
  lh[t] = 0; __syncthreads();
  for (int i = blockIdx.x * 256 + t; i < N_NODES; i += gridDim.x * 256)
    atomicAdd(&lh[batch[i]], 1);
  __syncthreads();
  if (lh[t]) atomicAdd(&gcnt[t], lh[t]);
}

__global__ void k_gscan(const int* __restrict__ gcnt, int* __restrict__ gstart) {
  __shared__ int lds[NGRAPH];
  int t = threadIdx.x;
  int v = gcnt[t]; lds[t] = v; __syncthreads();
  for (int off = 1; off < NGRAPH; off <<= 1) {
    int x = (t >= off) ? lds[t - off] : 0;
    __syncthreads();
    lds[t] += x;
    __syncthreads();
  }
  gstart[t] = lds[t] - v;            // exclusive
  if (t == NGRAPH - 1) gstart[NGRAPH] = lds[NGRAPH - 1];
}

// -------- weight concat TRANSPOSED fp16, K zero-padded to 64: Wct[p][f] -------
// p<192 : Yh col p -> o=p>>3, k8=p&7 -> W[k8][f][o]
// p>=192: q=p-192, o=q>>1, (q&1)? B[f][o] : A[f][o]   (A,B interleaved pairs)
__global__ void k_wcat_h(const float* __restrict__ W, const float* __restrict__ A,
                         const float* __restrict__ B, __half* __restrict__ out,
                         int din) {
  int i = blockIdx.x * blockDim.x + threadIdx.x;
  if (i >= YCOLS * 64) return;
  int p = i / 64, f = i % 64;
  float v = 0.f;
  if (f < din) {
    if (p < 192) { int o = p >> 3, k8 = p & 7; v = W[(k8 * din + f) * 24 + o]; }
    else {
      int q = p - 192, o = q >> 1;
      v = (q & 1) ? B[f * 24 + o] : A[f * 24 + o];
    }
  }
  out[i] = __float2half(v);
}

// ---------------- MFMA GEMM, operand-swapped: D = Wct_tile · X_tile ----------
// Lane's 4 accs = 4 consecutive output cols for ONE x-row -> direct 8B stores.
template <int F>
__global__ __launch_bounds__(256) void k_mm(const float* __restrict__ X,
                                            const __half* __restrict__ Wct,
                                            const float* __restrict__ ss,
                                            const float* __restrict__ ba,
                                            const float* __restrict__ bc,
                                            __half* __restrict__ Yh,
                                            float* __restrict__ h) {
  __shared__ _Float16 sx[64][64];
  int t = threadIdx.x;
  int r0 = blockIdx.x * 64;
  constexpr int F4 = F / 4;
  for (int i = t; i < 64 * F4; i += 256) {
    int row = i / F4, c4 = i - row * F4;
    int grow = r0 + row;
    float4 v = make_float4(0.f, 0.f, 0.f, 0.f);
    if (grow < N_NODES) {
      v = *reinterpret_cast<const float4*>(X + (size_t)grow * F + c4 * 4);
      if (ss) {
        int f = c4 * 4;
        v.x = v.x * ss[f + 0] + ss[48 + f + 0];
        v.y = v.y * ss[f + 1] + ss[48 + f + 1];
        v.z = v.z * ss[f + 2] + ss[48 + f + 2];
        v.w = v.w * ss[f + 3] + ss[48 + f + 3];
      }
    }
    int c = c4 * 4;
    sx[row][c + 0] = (_Float16)v.x;
    sx[row][c + 1] = (_Float16)v.y;
    sx[row][c + 2] = (_Float16)v.z;
    sx[row][c + 3] = (_Float16)v.w;
  }
  if (F == 48) {   // zero-pad K 48..63
    for (int i = t; i < 64 * 16; i += 256) {
      int row = i / 16, k = 48 + (i % 16);
      sx[row][k] = (_Float16)0.f;
    }
  }
  __syncthreads();

  int w = t >> 6, l = t & 63;
  int lo = l & 15;            // A-row (weight col within tile) AND B-col (x row)
  int lk = (l >> 4) * 8;      // k-slice
  int g  = l >> 4;            // acc group: lane holds output cols tile*16+4g..+3
  const f16x8 xb0 = *reinterpret_cast<const f16x8*>(&sx[w * 16 + lo][lk]);
  const f16x8 xb1 = *reinterpret_cast<const f16x8*>(&sx[w * 16 + lo][lk + 32]);
  const _Float16* wct = reinterpret_cast<const _Float16*>(Wct);
  int xg = r0 + w * 16 + lo;  // this lane's global x-row (for stores)

#pragma unroll
  for (int tt = 0; tt < 15; tt++) {
    const f16x8 a0 = *reinterpret_cast<const f16x8*>(wct + (tt * 16 + lo) * 64 + lk);
    const f16x8 a1 = *reinterpret_cast<const f16x8*>(wct + (tt * 16 + lo) * 64 + lk + 32);
    f32x4 acc = {0.f, 0.f, 0.f, 0.f};
    acc = __builtin_amdgcn_mfma_f32_16x16x32_f16(a0, xb0, acc, 0, 0, 0);
    acc = __builtin_amdgcn_mfma_f32_16x16x32_f16(a1, xb1, acc, 0, 0, 0);
    if (xg < N_NODES) {
      if (tt < 12) {
        union { __half h4[4]; uint2 u; } pk;
        pk.h4[0] = __float2half(acc[0]);
        pk.h4[1] = __float2half(acc[1]);
        pk.h4[2] = __float2half(acc[2]);
        pk.h4[3] = __float2half(acc[3]);
        *reinterpret_cast<uint2*>(Yh + (size_t)xg * 192 + tt * 16 + g * 4) = pk.u;
      } else {
        int o0 = (tt - 12) * 8 + g * 2;
        float g0 = fmaxf(acc[0] + ba[o0], 0.f) * tanhf(acc[1] + bc[o0]);
        float g1 = fmaxf(acc[2] + ba[o0 + 1], 0.f) * tanhf(acc[3] + bc[o0 + 1]);
        *reinterpret_cast<float2*>(h + (size_t)xg * 48 + 24 + o0) = make_float2(g0, g1);
      }
    }
  }
}

// ---------------- edge aggregation (conv half of h only) ----------------
// block = 192 threads = 2 nodes x (4 edge-slots x 24 channels), CSR order, unroll-4
__global__ __launch_bounds__(192) void k_agg(
    const __half* __restrict__ Yh, const int* __restrict__ rowptr,
    const int* __restrict__ esrc, const __half* __restrict__ ea_csr,
    const float* __restrict__ bconv, float* __restrict__ h) {
  __shared__ float lacc[2][4][24];
  int t = threadIdx.x;
  int ln   = t / 96;            // local node 0/1
  int slot = (t / 24) % 4;      // edge slot 0..3
  int o    = t % 24;            // channel
  int n = blockIdx.x * 2 + ln;
  float acc = 0.f;
  if (n < N_NODES) {
    int r0 = rowptr[n], r1 = rowptr[n + 1];
    int idx = r0 + slot;
    for (; idx + 12 < r1; idx += 16) {
      int s0 = esrc[idx], s1 = esrc[idx + 4], s2 = esrc[idx + 8], s3 = esrc[idx + 12];
      float4 e0 = *reinterpret_cast<const float4*>(ea_csr + (size_t)idx * 8);
      float4 e1 = *reinterpret_cast<const float4*>(ea_csr + (size_t)(idx + 4) * 8);
      float4 e2 = *reinterpret_cast<const float4*>(ea_csr + (size_t)(idx + 8) * 8);
      float4 e3 = *reinterpret_cast<const float4*>(ea_csr + (size_t)(idx + 12) * 8);
      float4 y0 = *reinterpret_cast<const float4*>(Yh + (size_t)s0 * 192 + o * 8);
      float4 y1 = *reinterpret_cast<const float4*>(Yh + (size_t)s1 * 192 + o * 8);
      float4 y2 = *reinterpret_cast<const float4*>(Yh + (size_t)s2 * 192 + o * 8);
      float4 y3 = *reinterpret_cast<const float4*>(Yh + (size_t)s3 * 192 + o * 8);
      acc = dot8(y0, e0, acc);
      acc = dot8(y1, e1, acc);
      acc = dot8(y2, e2, acc);
      acc = dot8(y3, e3, acc);
    }
    for (; idx < r1; idx += 4) {
      int s0 = esrc[idx];
      float4 e0 = *reinterpret_cast<const float4*>(ea_csr + (size_t)idx * 8);
      float4 y0 = *reinterpret_cast<const float4*>(Yh + (size_t)s0 * 192 + o * 8);
      acc = dot8(y0, e0, acc);
    }
  }
  lacc[ln][slot][o] = acc;
  __syncthreads();
  if (t < 48) {                 // t = ln2*24 + oo
    int ln2 = t / 24, oo = t % 24;
    int n2 = blockIdx.x * 2 + ln2;
    if (n2 < N_NODES) {
      float a = lacc[ln2][0][oo] + lacc[ln2][1][oo] + lacc[ln2][2][oo] + lacc[ln2][3][oo];
      h[(size_t)n2 * 48 + oo] = fmaxf(a + bconv[oo], 0.f);
    }
  }
}

// ---------------- BN stats stage 1: coalesced reduce of h ----------------
__global__ __launch_bounds__(192) void k_bnred1(const float* __restrict__ h,
                                                float* __restrict__ out) {
  __shared__ float lsum[192], lsq[192];
  int t = threadIdx.x;
  int rp = t / 48, c = t % 48;
  int r0 = blockIdx.x * BNCHUNK;
  int r1 = r0 + BNCHUNK; if (r1 > N_NODES) r1 = N_NODES;
  float s = 0.f, q = 0.f;
  for (int r = r0 + rp; r < r1; r += 4) {
    float v = h[(size_t)r * 48 + c];
    s += v; q += v * v;
  }
  lsum[t] = s; lsq[t] = q; __syncthreads();
  if (t < 48) {
    float S = lsum[t] + lsum[t + 48] + lsum[t + 96] + lsum[t + 144];
    float Q = lsq[t] + lsq[t + 48] + lsq[t + 96] + lsq[t + 144];
    out[(size_t)blockIdx.x * 96 + t] = S;
    out[(size_t)blockIdx.x * 96 + 48 + t] = Q;
  }
}

// ---------------- BN stats stage 2 -> scale/shift ----------------
__global__ void k_bnstats(const float* __restrict__ partial, int nblk,
                          const float* __restrict__ g, const float* __restrict__ be,
                          float* __restrict__ ss) {
  __shared__ float ls[256], lq[256];
  int c = blockIdx.x, t = threadIdx.x;
  float s = 0.f, q = 0.f;
  for (int i = t; i < nblk; i += 256) { s += partial[(size_t)i * 96 + c]; q += partial[(size_t)i * 96 + 48 + c]; }
  ls[t] = s; lq[t] = q; __syncthreads();
  for (int off = 128; off > 0; off >>= 1) {
    if (t < off) { ls[t] += ls[t + off]; lq[t] += lq[t + off]; }
    __syncthreads();
  }
  if (t == 0) {
    float mean = ls[0] / (float)N_NODES;
    float var = lq[0] / (float)N_NODES - mean * mean;
    var = fmaxf(var, 0.f);
    float sc = g[c] * rsqrtf(var + EPS);
    ss[c] = sc;
    ss[48 + c] = be[c] - mean * sc;
  }
}

// ---------------- mean pool: one block per graph, zero atomics ----------------
__global__ __launch_bounds__(240) void k_pool2(const float* __restrict__ h,
                                               const int* __restrict__ gstart,
                                               const float* __restrict__ ss,
                                               float* __restrict__ pooled) {
  __shared__ float acc[240];
  int g = blockIdx.x, t = threadIdx.x;
  int o = t % 48, r = t / 48;           // 5 row-groups x 48 channels
  int n0 = gstart[g], n1 = gstart[g + 1];
  float s = 0.f;
  for (int n = n0 + r; n < n1; n += 5) s += h[(size_t)n * 48 + o];
  acc[t] = s; __syncthreads();
  if (t < 48) {
    float tot = acc[t] + acc[t + 48] + acc[t + 96] + acc[t + 144] + acc[t + 192];
    float cnt = (float)(n1 - n0);
    float mean = tot / fmaxf(cnt, 1.f);
    pooled[g * 48 + t] = mean * ss[t] + ss[48 + t];
  }
}

// ---------------- final MLP: relu(p@F1+f1)@F2+f2 ----------------
__global__ __launch_bounds__(64) void k_mlp(const float* __restrict__ pooled,
                                            const float* __restrict__ F1,
                                            const float* __restrict__ f1,
                                            const float* __restrict__ F2,
                                            const float* __restrict__ f2,
                                            float* __restrict__ out) {
  __shared__ float p[48];
  int g = blockIdx.x, t = threadIdx.x;
  if (t < 48) p[t] = pooled[g * 48 + t];
  __syncthreads();
  float r = 0.f;
  if (t < 32) {
    float s = f1[t];
#pragma unroll
    for (int c = 0; c < 48; c++) s += p[c] * F1[c * 32 + t];
    r = fmaxf(s, 0.f) * F2[t];
  }
  for (int off = 32; off > 0; off >>= 1) r += __shfl_down(r, off, 64);
  if (t == 0) out[g] = r + f2[0];
}

extern "C" void kernel_launch(void* const* d_in, const int* in_sizes, int n_in,
                              void* d_out, int out_size, void* d_ws, size_t ws_size,
                              hipStream_t stream) {
  const float* x          = (const float*)d_in[0];
  const int*   edge_index = (const int*)d_in[1];
  const float* ea         = (const float*)d_in[2];
  const int*   batch      = (const int*)d_in[3];
  const float *W[3], *bcv[3], *A[3], *ba[3], *B[3], *bc[3], *g[3], *be[3];
  for (int l = 0; l < 3; l++) {
    int base = 4 + l * 8;
    W[l]   = (const float*)d_in[base + 0];
    bcv[l] = (const float*)d_in[base + 1];
    A[l]   = (const float*)d_in[base + 2];
    ba[l]  = (const float*)d_in[base + 3];
    B[l]   = (const float*)d_in[base + 4];
    bc[l]  = (const float*)d_in[base + 5];
    g[l]   = (const float*)d_in[base + 6];
    be[l]  = (const float*)d_in[base + 7];
  }
  const float* F1 = (const float*)d_in[28];
  const float* f1 = (const float*)d_in[29];
  const float* F2 = (const float*)d_in[30];
  const float* f2 = (const float*)d_in[31];
  const int* src = edge_index;
  const int* dst = edge_index + N_EDGES;

  char* w = (char*)d_ws;
  auto alloc = [&](size_t bytes) -> char* {
    char* p = w;
    w += (bytes + 255) & ~(size_t)255;
    return p;
  };
  int nagg = (N_NODES + 1) / 2;                   // 50000 blocks, 2 nodes each
  int nred = (N_NODES + BNCHUNK - 1) / BNCHUNK;   // 500 stage-1 blocks

  int*    rowptr  = (int*)alloc((N_NODES + 1) * 4);
  int*    cursor  = (int*)alloc((size_t)N_NODES * 4);
  int*    deg     = (int*)alloc((size_t)N_NODES * 4);
  int*    bsum    = (int*)alloc(128 * 4);
  int*    esrc    = (int*)alloc((size_t)N_EDGES * 4);
  __half* ea_csr  = (__half*)alloc((size_t)N_EDGES * 8 * 2);
  int*    gcnt    = (int*)alloc(NGRAPH * 4);
  int*    gstart  = (int*)alloc((NGRAPH + 1) * 4);
  __half* Wct1    = (__half*)alloc((size_t)YCOLS * 64 * 2);
  __half* Wct2    = (__half*)alloc((size_t)YCOLS * 64 * 2);
  __half* Wct3    = (__half*)alloc((size_t)YCOLS * 64 * 2);
  __half* Yh      = (__half*)alloc((size_t)N_NODES * 192 * 2);
  float*  h0      = (float*)alloc((size_t)N_NODES * 48 * 4);
  float*  h1      = (float*)alloc((size_t)N_NODES * 48 * 4);
  float*  partial2= (float*)alloc((size_t)nred * 96 * 4);
  float*  ss1     = (float*)alloc(96 * 4);
  float*  ss2     = (float*)alloc(96 * 4);
  float*  ss3     = (float*)alloc(96 * 4);
  float*  pooled  = (float*)alloc(NGRAPH * 48 * 4);

  hipMemsetAsync(deg, 0, (size_t)N_NODES * 4, stream);
  hipMemsetAsync(gcnt, 0, NGRAPH * 4, stream);

  k_count<<<(N_EDGES + 255) / 256, 256, 0, stream>>>(dst, deg);
  int nchunk = (N_NODES + 1023) / 1024;
  k_scan1<<<nchunk, 256, 0, stream>>>(deg, rowptr, bsum);
  k_scan2<<<1, 128, 0, stream>>>(bsum, nchunk);
  k_scan3<<<(N_NODES + 255) / 256, 256, 0, stream>>>(rowptr, bsum, cursor);
  k_fill<<<(N_EDGES + 255) / 256, 256, 0, stream>>>(src, dst, ea, cursor, esrc, ea_csr);

  k_ghist<<<64, 256, 0, stream>>>(batch, gcnt);
  k_gscan<<<1, NGRAPH, 0, stream>>>(gcnt, gstart);

  k_wcat_h<<<(YCOLS * 64 + 255) / 256, 256, 0, stream>>>(W[0], A[0], B[0], Wct1, 64);
  k_wcat_h<<<(YCOLS * 64 + 255) / 256, 256, 0, stream>>>(W[1], A[1], B[1], Wct2, 48);
  k_wcat_h<<<(YCOLS * 64 + 255) / 256, 256, 0, stream>>>(W[2], A[2], B[2], Wct3, 48);

  int nmm = (N_NODES + 63) / 64;   // 1563 blocks, 64 rows each

  // layer 1: x -> h0
  k_mm<64><<<nmm, 256, 0, stream>>>(x, Wct1, nullptr, ba[0], bc[0], Yh, h0);
  k_agg<<<nagg, 192, 0, stream>>>(Yh, rowptr, esrc, ea_csr, bcv[0], h0);
  k_bnred1<<<nred, 192, 0, stream>>>(h0, partial2);
  k_bnstats<<<48, 256, 0, stream>>>(partial2, nred, g[0], be[0], ss1);
  // layer 2: h0 (BN1 fold) -> h1
  k_mm<48><<<nmm, 256, 0, stream>>>(h0, Wct2, ss1, ba[1], bc[1], Yh, h1);
  k_agg<<<nagg, 192, 0, stream>>>(Yh, rowptr, esrc, ea_csr, bcv[1], h1);
  k_bnred1<<<nred, 192, 0, stream>>>(h1, partial2);
  k_bnstats<<<48, 256, 0, stream>>>(partial2, nred, g[1], be[1], ss2);
  // layer 3: h1 (BN2 fold) -> h0
  k_mm<48><<<nmm, 256, 0, stream>>>(h1, Wct3, ss2, ba[2], bc[2], Yh, h0);
  k_agg<<<nagg, 192, 0, stream>>>(Yh, rowptr, esrc, ea_csr, bcv[2], h0);
  k_bnred1<<<nred, 192, 0, stream>>>(h0, partial2);
  k_bnstats<<<48, 256, 0, stream>>>(partial2, nred, g[2], be[2], ss3);

  // pool (BN3 fold via mean) + MLP head
  k_pool2<<<NGRAPH, 240, 0, stream>>>(h0, gstart, ss3, pooled);
  k_mlp<<<NGRAPH, 64, 0, stream>>>(pooled, F1, f1, F2, f2, (float*)d_out);
}